// Round 21
// baseline (71.689 us; speedup 1.0000x reference)
//
#include <hip/hip_runtime.h>

#define N_NODES 10000
#define N_EDGES 320000
#define DIN 256
#define DOUT 256
#define SEGSZ 32    // slots per sub-counter segment (3 segs x 32 = 96/node)
#define CFB 1250    // count_fill blocks (320000/256 exactly)
#define GEMB 628    // gemm blocks: 157 row-tiles x 4 col-strips
#define M_PAD 10048 // 157*64

typedef short bf16x8 __attribute__((ext_vector_type(8)));
typedef float f32x4 __attribute__((ext_vector_type(4)));

__device__ __forceinline__ unsigned bfrne(float f) {  // f32 -> bf16 bits (RNE)
    unsigned u = __float_as_uint(f);
    return (u + 0x7fffu + ((u >> 16) & 1u)) >> 16;
}
__device__ __forceinline__ float blo(unsigned u) { return __uint_as_float(u << 16); }
__device__ __forceinline__ float bhi(unsigned u) { return __uint_as_float(u & 0xffff0000u); }

// ---------- K1: xb = bf16(x), Wt = bf16(W^T), cnt3 = 0 (R16 prep, exact) ----------
#define NX4 (N_NODES * 64)  // 640000 x-quads
#define NW4 (DIN * 64)      // 16384 W-quads
#define NC3 (N_NODES * 3)   // 30000 sub-counters
#define PREP_TOTAL (NX4 + NW4 + NC3)
__global__ __launch_bounds__(256) void prep_kernel(
    const float4* __restrict__ x4, const float4* __restrict__ W4,
    uint2* __restrict__ xb4, ushort* __restrict__ Wt, int* __restrict__ cnt3) {
    int g = blockIdx.x * blockDim.x + threadIdx.x;
    if (g < NX4) {
        float4 v = x4[g];
        uint2 o;
        o.x = bfrne(v.x) | (bfrne(v.y) << 16);
        o.y = bfrne(v.z) | (bfrne(v.w) << 16);
        xb4[g] = o;
    } else if (g < NX4 + NW4) {
        int g3 = g - NX4;
        int k = g3 >> 6;
        int c0 = (g3 & 63) * 4;
        float4 w = W4[g3];  // W[k][c0..c0+3], coalesced
        Wt[(c0 + 0) * DIN + k] = (ushort)bfrne(w.x);
        Wt[(c0 + 1) * DIN + k] = (ushort)bfrne(w.y);
        Wt[(c0 + 2) * DIN + k] = (ushort)bfrne(w.z);
        Wt[(c0 + 3) * DIN + k] = (ushort)bfrne(w.w);
    } else if (g < PREP_TOTAL) {
        cnt3[g - NX4 - NW4] = 0;
    }
}

// ---------- K2: fused [count_fill | dense GEMM U = xb @ W] ----------
// blocks [0, CFB): CF, exactly R16's 3-way split-counter atomic pass.
// blocks [CFB, CFB+GEMB): MFMA GEMM, hidden under CF's atomic-stall window.
__global__ __launch_bounds__(256) void cf_gemm_kernel(
    const int* __restrict__ src, const int* __restrict__ dst,
    int* __restrict__ cnt3, int* __restrict__ slot,
    const ushort* __restrict__ xb, const ushort* __restrict__ Wt,
    ushort* __restrict__ U) {
    const int bid = blockIdx.x;
    const int tid = threadIdx.x;

    if (bid < CFB) {
        // ---- count+fill (R16 exact) ----
        int e = bid * 256 + tid;  // CFB*256 == N_EDGES exactly
        int s = src[e];
        int c = e % 3;
        int p = atomicAdd(&cnt3[s * 3 + c], 1);
        if (p < SEGSZ) slot[s * 96 + c * SEGSZ + p] = dst[e];
        return;
    }

    // ---- GEMM: block covers 64 rows x 64 cols of U ----
    int gb = bid - CFB;
    int rt = gb >> 2;   // row-tile 0..156
    int cs = gb & 3;    // col-strip 0..3
    int w = tid >> 6;
    int lane = tid & 63;
    int r = lane & 15;
    int gq = lane >> 4;

    int arow = rt * 64 + w * 16 + r;              // A row for this lane
    const ushort* ap = xb + arow * DIN + gq * 8;  // A frag base
    const ushort* wp0 = Wt + (cs * 64 + 0 * 16 + r) * DIN + gq * 8;
    const ushort* wp1 = Wt + (cs * 64 + 1 * 16 + r) * DIN + gq * 8;
    const ushort* wp2 = Wt + (cs * 64 + 2 * 16 + r) * DIN + gq * 8;
    const ushort* wp3 = Wt + (cs * 64 + 3 * 16 + r) * DIN + gq * 8;

    f32x4 acc0 = {0.f, 0.f, 0.f, 0.f};
    f32x4 acc1 = {0.f, 0.f, 0.f, 0.f};
    f32x4 acc2 = {0.f, 0.f, 0.f, 0.f};
    f32x4 acc3 = {0.f, 0.f, 0.f, 0.f};
#pragma unroll
    for (int k8 = 0; k8 < 8; ++k8) {
        int koff = k8 * 32;
        bf16x8 a = {};
        if (arow < N_NODES) a = *(const bf16x8*)(ap + koff);
        acc0 = __builtin_amdgcn_mfma_f32_16x16x32_bf16(a, *(const bf16x8*)(wp0 + koff), acc0, 0, 0, 0);
        acc1 = __builtin_amdgcn_mfma_f32_16x16x32_bf16(a, *(const bf16x8*)(wp1 + koff), acc1, 0, 0, 0);
        acc2 = __builtin_amdgcn_mfma_f32_16x16x32_bf16(a, *(const bf16x8*)(wp2 + koff), acc2, 0, 0, 0);
        acc3 = __builtin_amdgcn_mfma_f32_16x16x32_bf16(a, *(const bf16x8*)(wp3 + koff), acc3, 0, 0, 0);
    }

    // C/D: col = lane&15, row = gq*4 + i. U has M_PAD rows; pad rows never read.
    int orow0 = rt * 64 + w * 16 + gq * 4;
#pragma unroll
    for (int i = 0; i < 4; ++i) {
        int ro = (orow0 + i) * DOUT + cs * 64 + r;
        U[ro + 0 * 16] = (ushort)bfrne(acc0[i]);
        U[ro + 1 * 16] = (ushort)bfrne(acc1[i]);
        U[ro + 2 * 16] = (ushort)bfrne(acc2[i]);
        U[ro + 3 * 16] = (ushort)bfrne(acc3[i]);
    }
}

// ---------- K3: pure gather over U + bias + relu -> out ----------
// block = 256 thr = 4 waves = 8 nodes; 1250 blocks. Half-wave owns one node:
// lane covers 8 exclusive channels (uint4); R16's proven 3-segment 2-deep
// pipelined gather; no LDS, no MFMA, no barriers; coalesced float4 out stores.
// out_i = relu(d_i*(sum_j d_j*U_j + d_i*U_i) + b)
__global__ __launch_bounds__(256, 8) void gather_kernel(
    const uint4* __restrict__ Uq, const int* __restrict__ cnt3,
    const int* __restrict__ slot, const float* __restrict__ bias,
    float* __restrict__ out) {
    const int tid = threadIdx.x;
    const int w = tid >> 6;
    const int lane = tid & 63;
    const int half = lane >> 5;
    const int hl = lane & 31;  // channel group: ch [hl*8, hl*8+8)
    const int node = blockIdx.x * 8 + w * 2 + half;

    int c0 = cnt3[node * 3 + 0];
    int c1 = cnt3[node * 3 + 1];
    int c2 = cnt3[node * 3 + 2];
    int dg = c0 + c1 + c2;
    float di = rsqrtf((float)dg);
    int s0 = min(c0, SEGSZ), s1 = min(c1, SEGSZ), s2 = min(c2, SEGSZ);
    int base = node * 96;

    int jA = 0, jB = 0, jC = 0;
    float vA = 0.f, vB = 0.f, vC = 0.f;
    if (hl < s0) {
        jA = slot[base + hl];
        vA = rsqrtf((float)(cnt3[jA * 3] + cnt3[jA * 3 + 1] + cnt3[jA * 3 + 2]));
    }
    if (hl < s1) {
        jB = slot[base + SEGSZ + hl];
        vB = rsqrtf((float)(cnt3[jB * 3] + cnt3[jB * 3 + 1] + cnt3[jB * 3 + 2]));
    }
    if (hl < s2) {
        jC = slot[base + 2 * SEGSZ + hl];
        vC = rsqrtf((float)(cnt3[jC * 3] + cnt3[jC * 3 + 1] + cnt3[jC * 3 + 2]));
    }

    float a0 = 0.f, a1 = 0.f, a2 = 0.f, a3 = 0.f,
          a4 = 0.f, a5 = 0.f, a6 = 0.f, a7 = 0.f;

#define ACC(c_, d_) {                                      \
    a0 += (d_) * blo((c_).x); a1 += (d_) * bhi((c_).x);    \
    a2 += (d_) * blo((c_).y); a3 += (d_) * bhi((c_).y);    \
    a4 += (d_) * blo((c_).z); a5 += (d_) * bhi((c_).z);    \
    a6 += (d_) * blo((c_).w); a7 += (d_) * bhi((c_).w);    \
}
#define SEGGATHER(jX_, vX_, sX_) {                                  \
    if ((sX_) > 0) {                                                \
        int jj = __shfl(jX_, half * 32, 64);                        \
        float dd = __shfl(vX_, half * 32, 64);                      \
        uint4 cur = Uq[jj * 32 + hl];                               \
        for (int t = 1; t < (sX_); ++t) {                           \
            int jn = __shfl(jX_, half * 32 + t, 64);                \
            float dn = __shfl(vX_, half * 32 + t, 64);              \
            uint4 nxt = Uq[jn * 32 + hl];  /* issue before use */   \
            ACC(cur, dd);                                           \
            cur = nxt; dd = dn;                                     \
        }                                                           \
        ACC(cur, dd);                                               \
    }                                                               \
}

    SEGGATHER(jA, vA, s0);
    SEGGATHER(jB, vB, s1);
    SEGGATHER(jC, vC, s2);

    // self term + final scale
    uint4 sv = Uq[node * 32 + hl];
    a0 = di * (a0 + di * blo(sv.x)); a1 = di * (a1 + di * bhi(sv.x));
    a2 = di * (a2 + di * blo(sv.y)); a3 = di * (a3 + di * bhi(sv.y));
    a4 = di * (a4 + di * blo(sv.z)); a5 = di * (a5 + di * bhi(sv.z));
    a6 = di * (a6 + di * blo(sv.w)); a7 = di * (a7 + di * bhi(sv.w));

    const float4* b4 = (const float4*)bias;
    float4 bv0 = b4[hl * 2];
    float4 bv1 = b4[hl * 2 + 1];
    float4 o0, o1;
    o0.x = fmaxf(a0 + bv0.x, 0.f); o0.y = fmaxf(a1 + bv0.y, 0.f);
    o0.z = fmaxf(a2 + bv0.z, 0.f); o0.w = fmaxf(a3 + bv0.w, 0.f);
    o1.x = fmaxf(a4 + bv1.x, 0.f); o1.y = fmaxf(a5 + bv1.y, 0.f);
    o1.z = fmaxf(a6 + bv1.z, 0.f); o1.w = fmaxf(a7 + bv1.w, 0.f);
    *(float4*)&out[node * DOUT + hl * 8] = o0;
    *(float4*)&out[node * DOUT + hl * 8 + 4] = o1;
}

extern "C" void kernel_launch(void* const* d_in, const int* in_sizes, int n_in,
                              void* d_out, int out_size, void* d_ws, size_t ws_size,
                              hipStream_t stream) {
    const float* x = (const float*)d_in[0];
    const int* edge_index = (const int*)d_in[1];
    const float* W = (const float*)d_in[2];
    const float* b = (const float*)d_in[3];
    float* out = (float*)d_out;

    const int* src = edge_index;            // edge_index[0, :]
    const int* dst = edge_index + N_EDGES;  // edge_index[1, :]

    char* ws = (char*)d_ws;
    int* cnt3   = (int*)(ws + 0);           // 120,000 B ([10000][3] sub-counters)
    int* slot   = (int*)(ws + 120064);      // 3,840,000 B (10000 x 96, 3 segs x 32)
    ushort* xb  = (ushort*)(ws + 3960064);  // 5,120,000 B (bf16 10000 x 256)
    ushort* Wt  = (ushort*)(ws + 9080064);  // 131,072 B  (bf16 256x256 transposed)
    ushort* U   = (ushort*)(ws + 9211136);  // 5,144,576 B (bf16 10048 x 256) -> ~14.4 MB

    prep_kernel<<<(PREP_TOTAL + 255) / 256, 256, 0, stream>>>(
        (const float4*)x, (const float4*)W, (uint2*)xb, Wt, cnt3);
    cf_gemm_kernel<<<CFB + GEMB, 256, 0, stream>>>(src, dst, cnt3, slot, xb, Wt, U);
    gather_kernel<<<N_NODES / 8, 256, 0, stream>>>(
        (const uint4*)U, cnt3, slot, b, out);
}

// Round 22
// 63.442 us; speedup vs baseline: 1.1300x; 1.1300x over previous
//
#include <hip/hip_runtime.h>

#define N_NODES 10000
#define N_EDGES 320000
#define DIN 256
#define DOUT 256
#define SEGSZ 32   // slots per sub-counter segment (3 segs x 32 = 96/node)
#define LDA 264    // LDS A-tile row stride (ushorts)

typedef short bf16x8 __attribute__((ext_vector_type(8)));
typedef float f32x4 __attribute__((ext_vector_type(4)));

__device__ __forceinline__ unsigned bfrne(float f) {  // f32 -> bf16 bits (RNE)
    unsigned u = __float_as_uint(f);
    return (u + 0x7fffu + ((u >> 16) & 1u)) >> 16;
}
__device__ __forceinline__ float blo(unsigned u) { return __uint_as_float(u << 16); }
__device__ __forceinline__ float bhi(unsigned u) { return __uint_as_float(u & 0xffff0000u); }

// ---------- K1: xb = bf16(x), Wt = bf16(W^T), cnt3 = 0 ----------
#define NX4 (N_NODES * 64)  // 640000 x-quads
#define NW4 (DIN * 64)      // 16384 W-quads
#define NC3 (N_NODES * 3)   // 30000 sub-counters
#define PREP_TOTAL (NX4 + NW4 + NC3)
__global__ __launch_bounds__(256) void prep_kernel(
    const float4* __restrict__ x4, const float4* __restrict__ W4,
    uint2* __restrict__ xb4, ushort* __restrict__ Wt, int* __restrict__ cnt3) {
    int g = blockIdx.x * blockDim.x + threadIdx.x;
    if (g < NX4) {
        float4 v = x4[g];
        uint2 o;
        o.x = bfrne(v.x) | (bfrne(v.y) << 16);
        o.y = bfrne(v.z) | (bfrne(v.w) << 16);
        xb4[g] = o;
    } else if (g < NX4 + NW4) {
        int g3 = g - NX4;
        int k = g3 >> 6;
        int c0 = (g3 & 63) * 4;
        float4 w = W4[g3];  // W[k][c0..c0+3], coalesced
        Wt[(c0 + 0) * DIN + k] = (ushort)bfrne(w.x);
        Wt[(c0 + 1) * DIN + k] = (ushort)bfrne(w.y);
        Wt[(c0 + 2) * DIN + k] = (ushort)bfrne(w.z);
        Wt[(c0 + 3) * DIN + k] = (ushort)bfrne(w.w);
    } else if (g < PREP_TOTAL) {
        cnt3[g - NX4 - NW4] = 0;
    }
}

// ---------- K2: count+fill with 3-way split counters (contention / 3) ----------
__global__ __launch_bounds__(256) void count_fill_kernel(
    const int* __restrict__ src, const int* __restrict__ dst,
    int* __restrict__ cnt3, int* __restrict__ slot) {
    int e = blockIdx.x * blockDim.x + threadIdx.x;
    if (e < N_EDGES) {
        int s = src[e];
        int c = e % 3;
        int p = atomicAdd(&cnt3[s * 3 + c], 1);
        if (p < SEGSZ) slot[s * 96 + c * SEGSZ + p] = dst[e];
    }
}

// ---------- K3: fused aggregate (node-per-HALF-wave, 3 ragged segments) + MFMA GEMM ----------
// block = 512 thr = 8 waves = 16 nodes; 625 blocks; all waves co-resident.
__global__ __launch_bounds__(512, 8) void agg_gemm_kernel(
    const uint4* __restrict__ xbq, const int* __restrict__ cnt3,
    const int* __restrict__ slot, const ushort* __restrict__ Wt,
    const float* __restrict__ bias, float* __restrict__ out) {
    __shared__ ushort sA[16 * LDA];  // 8448 B

    const int tid = threadIdx.x;
    const int w = tid >> 6;
    const int lane = tid & 63;
    const int half = lane >> 5;  // which node of the wave's pair
    const int hl = lane & 31;    // channel group: ch [hl*8, hl*8+8)
    const int row = w * 2 + half;
    const int node = blockIdx.x * 16 + row;

    int c0 = cnt3[node * 3 + 0];
    int c1 = cnt3[node * 3 + 1];
    int c2 = cnt3[node * 3 + 2];
    int dg = c0 + c1 + c2;
    float di = rsqrtf((float)dg);
    int s0 = min(c0, SEGSZ), s1 = min(c1, SEGSZ), s2 = min(c2, SEGSZ);
    int base = node * 96;

    // preload segment neighbor lists + their dv (deg = sum of 3 sub-counts)
    int jA = 0, jB = 0, jC = 0;
    float vA = 0.f, vB = 0.f, vC = 0.f;
    if (hl < s0) {
        jA = slot[base + hl];
        vA = rsqrtf((float)(cnt3[jA * 3] + cnt3[jA * 3 + 1] + cnt3[jA * 3 + 2]));
    }
    if (hl < s1) {
        jB = slot[base + SEGSZ + hl];
        vB = rsqrtf((float)(cnt3[jB * 3] + cnt3[jB * 3 + 1] + cnt3[jB * 3 + 2]));
    }
    if (hl < s2) {
        jC = slot[base + 2 * SEGSZ + hl];
        vC = rsqrtf((float)(cnt3[jC * 3] + cnt3[jC * 3 + 1] + cnt3[jC * 3 + 2]));
    }

    float a0 = 0.f, a1 = 0.f, a2 = 0.f, a3 = 0.f,
          a4 = 0.f, a5 = 0.f, a6 = 0.f, a7 = 0.f;

#define ACC(c_, d_) {                                      \
    a0 += (d_) * blo((c_).x); a1 += (d_) * bhi((c_).x);    \
    a2 += (d_) * blo((c_).y); a3 += (d_) * bhi((c_).y);    \
    a4 += (d_) * blo((c_).z); a5 += (d_) * bhi((c_).z);    \
    a6 += (d_) * blo((c_).w); a7 += (d_) * bhi((c_).w);    \
}
    // 2-deep pipelined gather over one ragged segment (j/dv broadcast via shfl)
#define SEGGATHER(jX_, vX_, sX_) {                                  \
    if ((sX_) > 0) {                                                \
        int jj = __shfl(jX_, half * 32, 64);                        \
        float dd = __shfl(vX_, half * 32, 64);                      \
        uint4 cur = xbq[jj * 32 + hl];                              \
        for (int t = 1; t < (sX_); ++t) {                           \
            int jn = __shfl(jX_, half * 32 + t, 64);                \
            float dn = __shfl(vX_, half * 32 + t, 64);              \
            uint4 nxt = xbq[jn * 32 + hl];  /* issue before use */  \
            ACC(cur, dd);                                           \
            cur = nxt; dd = dn;                                     \
        }                                                           \
        ACC(cur, dd);                                               \
    }                                                               \
}

    SEGGATHER(jA, vA, s0);
    SEGGATHER(jB, vB, s1);
    SEGGATHER(jC, vC, s2);

    // self term + final scale: agg = di*(sum + di*self); channels are lane-exclusive
    uint4 sv = xbq[node * 32 + hl];
    a0 = di * (a0 + di * blo(sv.x)); a1 = di * (a1 + di * bhi(sv.x));
    a2 = di * (a2 + di * blo(sv.y)); a3 = di * (a3 + di * bhi(sv.y));
    a4 = di * (a4 + di * blo(sv.z)); a5 = di * (a5 + di * bhi(sv.z));
    a6 = di * (a6 + di * blo(sv.w)); a7 = di * (a7 + di * bhi(sv.w));

    uint4 o;
    o.x = bfrne(a0) | (bfrne(a1) << 16);
    o.y = bfrne(a2) | (bfrne(a3) << 16);
    o.z = bfrne(a4) | (bfrne(a5) << 16);
    o.w = bfrne(a6) | (bfrne(a7) << 16);
    *(uint4*)&sA[row * LDA + hl * 8] = o;

    __syncthreads();

    // ---- Phase B: wave w computes out cols [w*32, w*32+32) for the 16 rows ----
    // A frag: lane holds sA[row=lane&15][k=(lane>>4)*8 ..+8), shared by both col-tiles
    // C/D: col = lane&15, row = (lane>>4)*4 + reg
    int r = lane & 15;
    int gq = lane >> 4;
    const ushort* wp0 = Wt + (w * 32 + r) * DIN;
    const ushort* wp1 = Wt + (w * 32 + 16 + r) * DIN;
    f32x4 acc0 = {0.f, 0.f, 0.f, 0.f};
    f32x4 acc1 = {0.f, 0.f, 0.f, 0.f};
#pragma unroll
    for (int k8 = 0; k8 < 8; ++k8) {
        int koff = k8 * 32 + gq * 8;
        bf16x8 a = *(const bf16x8*)&sA[r * LDA + koff];
        acc0 = __builtin_amdgcn_mfma_f32_16x16x32_bf16(a, *(const bf16x8*)(wp0 + koff), acc0, 0, 0, 0);
        acc1 = __builtin_amdgcn_mfma_f32_16x16x32_bf16(a, *(const bf16x8*)(wp1 + koff), acc1, 0, 0, 0);
    }

    int rbase = blockIdx.x * 16 + gq * 4;
    int oc0 = w * 32 + r;
    int oc1 = oc0 + 16;
    float bv0 = bias[oc0];
    float bv1 = bias[oc1];
#pragma unroll
    for (int i = 0; i < 4; ++i) {
        out[(rbase + i) * DOUT + oc0] = fmaxf(acc0[i] + bv0, 0.f);
        out[(rbase + i) * DOUT + oc1] = fmaxf(acc1[i] + bv1, 0.f);
    }
}

extern "C" void kernel_launch(void* const* d_in, const int* in_sizes, int n_in,
                              void* d_out, int out_size, void* d_ws, size_t ws_size,
                              hipStream_t stream) {
    const float* x = (const float*)d_in[0];
    const int* edge_index = (const int*)d_in[1];
    const float* W = (const float*)d_in[2];
    const float* b = (const float*)d_in[3];
    float* out = (float*)d_out;

    const int* src = edge_index;            // edge_index[0, :]
    const int* dst = edge_index + N_EDGES;  // edge_index[1, :]

    char* ws = (char*)d_ws;
    int* cnt3   = (int*)(ws + 0);          // 120,000 B ([10000][3] sub-counters)
    int* slot   = (int*)(ws + 120064);     // 3,840,000 B (10000 x 96, 3 segs x 32)
    ushort* xb  = (ushort*)(ws + 3960064); // 5,120,000 B (bf16 10000 x 256)
    ushort* Wt  = (ushort*)(ws + 9080064); // 131,072 B  (bf16 256x256 transposed)

    prep_kernel<<<(PREP_TOTAL + 255) / 256, 256, 0, stream>>>(
        (const float4*)x, (const float4*)W, (uint2*)xb, Wt, cnt3);
    count_fill_kernel<<<(N_EDGES + 255) / 256, 256, 0, stream>>>(src, dst, cnt3, slot);
    agg_gemm_kernel<<<N_NODES / 16, 512, 0, stream>>>(
        (const uint4*)xb, cnt3, slot, Wt, b, out);
}